// Round 6
// baseline (102.235 us; speedup 1.0000x reference)
//
#include <hip/hip_runtime.h>
#include <hip/hip_cooperative_groups.h>
#include <hip/hip_bf16.h>
#include <math.h>

namespace cg = cooperative_groups;

// Problem constants
constexpr int kB  = 8;
constexpr int kTD = 128;
constexpr int kTE = 256;
constexpr int kH  = 512;

constexpr float kTwoLog2e = 2.8853900817779268f; // 2*log2(e)
constexpr float kLog2e    = 1.4426950408889634f;

constexpr int TM = 4;              // t-tile in attention phase

typedef __attribute__((ext_vector_type(8)))  short short8;   // 8 bf16 (4 VGPRs)
typedef __attribute__((ext_vector_type(16))) float f32x16;   // 32x32 acc

// round-to-nearest-even f32 -> bf16 (bit manip; no NaN inputs here)
__device__ __forceinline__ unsigned short f2bf(float x) {
    unsigned int u = __float_as_uint(x);
    return (unsigned short)((u + 0x7fffu + ((u >> 16) & 1u)) >> 16);
}
__device__ __forceinline__ float bf2f(unsigned short h) {
    return __uint_as_float(((unsigned int)h) << 16);
}

// ---- shared memory overlay --------------------------------------------------
struct SmemA {                       // GEMM phase: 59,904 B
    unsigned short Ahi[4][64][40];   // per-group A tiles (bf16 hi)
    unsigned short Alo[4][64][40];   // per-group A tiles (bf16 lo)
    unsigned short Bhi[64][40];      // shared W tile (K-major, hi)
    unsigned short Blo[64][40];      // shared W tile (K-major, lo)
    float Ws[32][68];                // fp32 W tile for in-LDS transpose
};
struct SmemB {                       // attention phase: 49,280 B
    float  part[3 * TM * kTE];       // score partials
    float4 wgt4[kTE];                // softmax weights, t-major
    float  red_mx[4][TM];
    float  red_sm[4][TM];
    float4 pctx[4][TM][128];         // context partial tree
};

// ---------------------------------------------------------------------------
// One cooperative kernel:
//  Phase A (blocks 0..95): both GEMMs via split-bf16 MFMA, 4 m-tiles/block
//    sharing one W tile. exp2 epilogue; enc -> packed-transposed ewt,
//    dec -> row-major dwc.  Block 96: mask decode.
//  grid.sync()
//  Phase B (all 256 blocks): scores -> softmax -> context for one (b, 4-t).
// ---------------------------------------------------------------------------
__global__ __launch_bounds__(1024, 4)
void mega_kernel(const float* __restrict__ enc, const float* __restrict__ dec,
                 const float* __restrict__ W1, const float* __restrict__ W2,
                 const void* __restrict__ mask_raw, const float* __restrict__ V,
                 float* __restrict__ ewt, float* __restrict__ dwc,
                 float* __restrict__ mask_f,
                 float* __restrict__ ctx_out, float* __restrict__ attn_out) {
    __shared__ __align__(16) union { SmemA a; SmemB b; } smem;
    __shared__ unsigned int s_gt1, s_flt;

    const int bx  = blockIdx.x;
    const int tid = threadIdx.x;

    // ======================= PHASE A ======================================
    if (bx < 96) {
        const bool is_enc = (bx < 64);
        const int base = is_enc ? bx : bx - 64;
        const int mq = base >> 3;          // m-quad
        const int nt = base & 7;
        const int n0 = nt * 64;
        const int g   = tid >> 8;          // group 0..3 (one m-tile each)
        const int lid = tid & 255;
        const int mt  = mq * 4 + g;        // m-tile index within source
        const float* Abase = is_enc ? (enc + (size_t)mt * 64 * kH)
                                    : (dec + (size_t)mt * 64 * kH);
        const float* W = is_enc ? W1 : W2;

        const int ar  = lid >> 2;          // A row 0..63
        const int akc = (lid & 3) * 8;     // A k-chunk of 8
        const int wkr = tid >> 4;          // W pass1 k-row (tid<512 -> 0..31)
        const int wnc = (tid & 15) * 4;    // W pass1 n-chunk of 4
        const int pn  = tid >> 2;          // W pass2 n (tid<256 -> 0..63)
        const int pkc = (tid & 3) * 8;     // W pass2 k-chunk of 8

        const int lane = tid & 63;
        const int gw   = (tid >> 6) & 3;   // wave within group
        const int wr   = gw >> 1, wc = gw & 1;
        const int col  = lane & 31, hi5 = lane >> 5;

        f32x16 acc = {};
        const float* Arow = Abase + (size_t)ar * kH;

        float4 a0p = *(const float4*)&Arow[akc];
        float4 a1p = *(const float4*)&Arow[akc + 4];
        float4 w0p = {};
        if (tid < 512) w0p = *(const float4*)&W[(size_t)wkr * kH + n0 + wnc];

        for (int step = 0; step < 16; ++step) {
            // ---- pass1: stage W fp32 + A hi/lo pack ----
            if (tid < 512) *(float4*)&smem.a.Ws[wkr][wnc] = w0p;
            {
                uint4 H, L;
                float f[8] = {a0p.x, a0p.y, a0p.z, a0p.w, a1p.x, a1p.y, a1p.z, a1p.w};
                unsigned short hs[8], ls[8];
                #pragma unroll
                for (int j = 0; j < 8; ++j) {
                    hs[j] = f2bf(f[j]);
                    ls[j] = f2bf(f[j] - bf2f(hs[j]));
                }
                H.x = hs[0] | (hs[1] << 16); H.y = hs[2] | (hs[3] << 16);
                H.z = hs[4] | (hs[5] << 16); H.w = hs[6] | (hs[7] << 16);
                L.x = ls[0] | (ls[1] << 16); L.y = ls[2] | (ls[3] << 16);
                L.z = ls[4] | (ls[5] << 16); L.w = ls[6] | (ls[7] << 16);
                *(uint4*)&smem.a.Ahi[g][ar][akc] = H;
                *(uint4*)&smem.a.Alo[g][ar][akc] = L;
            }
            __syncthreads();

            // ---- pass2: W transpose-read, split, K-major store ----
            if (tid < 256) {
                uint4 H, L;
                unsigned short hs[8], ls[8];
                #pragma unroll
                for (int j = 0; j < 8; ++j) {
                    float x = smem.a.Ws[pkc + j][pn];
                    hs[j] = f2bf(x);
                    ls[j] = f2bf(x - bf2f(hs[j]));
                }
                H.x = hs[0] | (hs[1] << 16); H.y = hs[2] | (hs[3] << 16);
                H.z = hs[4] | (hs[5] << 16); H.w = hs[6] | (hs[7] << 16);
                L.x = ls[0] | (ls[1] << 16); L.y = ls[2] | (ls[3] << 16);
                L.z = ls[4] | (ls[5] << 16); L.w = ls[6] | (ls[7] << 16);
                *(uint4*)&smem.a.Bhi[pn][pkc] = H;
                *(uint4*)&smem.a.Blo[pn][pkc] = L;
            }
            // prefetch next step (lands during MFMA phase)
            if (step < 15) {
                const int k1 = (step + 1) * 32;
                a0p = *(const float4*)&Arow[k1 + akc];
                a1p = *(const float4*)&Arow[k1 + akc + 4];
                if (tid < 512)
                    w0p = *(const float4*)&W[(size_t)(k1 + wkr) * kH + n0 + wnc];
            }
            __syncthreads();

            // ---- fragments + MFMA: 2 k-chunks x 3 split-products ----
            #pragma unroll
            for (int kc = 0; kc < 32; kc += 16) {
                const int ka = kc + hi5 * 8;
                short8 ah = *(const short8*)&smem.a.Ahi[g][wr * 32 + col][ka];
                short8 al = *(const short8*)&smem.a.Alo[g][wr * 32 + col][ka];
                short8 bh = *(const short8*)&smem.a.Bhi[wc * 32 + col][ka];
                short8 bl = *(const short8*)&smem.a.Blo[wc * 32 + col][ka];
                acc = __builtin_amdgcn_mfma_f32_32x32x16_bf16(ah, bh, acc, 0, 0, 0);
                acc = __builtin_amdgcn_mfma_f32_32x32x16_bf16(ah, bl, acc, 0, 0, 0);
                acc = __builtin_amdgcn_mfma_f32_32x32x16_bf16(al, bh, acc, 0, 0, 0);
            }
            __syncthreads();   // keep next-step staging off in-flight ds_reads
        }

        // ---- epilogue: exp2 + store ----
        const int h = n0 + wc * 32 + col;
        if (is_enc) {
            #pragma unroll
            for (int reg = 0; reg < 16; ++reg) {
                const int row = (reg & 3) + 8 * (reg >> 2) + 4 * hi5;
                const int gm = mt * 64 + wr * 32 + row;       // = b*256 + s
                const int bb = gm >> 8, sE = gm & 255;
                float val = __builtin_amdgcn_exp2f(acc[reg] * kTwoLog2e);
                ewt[(((size_t)bb * 128 + (h >> 2)) * 256 + sE) * 4 + (h & 3)] = val;
            }
        } else {
            #pragma unroll
            for (int reg = 0; reg < 16; ++reg) {
                const int row = (reg & 3) + 8 * (reg >> 2) + 4 * hi5;
                const int dm = mt * 64 + wr * 32 + row;       // = b*128 + t
                float val = __builtin_amdgcn_exp2f(acc[reg] * kTwoLog2e);
                dwc[(size_t)dm * kH + h] = val;
            }
        }
    } else if (bx == 96) {
        // ---- mask decode (layout auto-detect: int32 / byte / float) ----
        const unsigned int* w = (const unsigned int*)mask_raw;
        unsigned int gt1 = 0, flt = 0;
        if (tid < 512) {                  // first 2048 B safe under every layout
            unsigned int v = w[tid];
            if (v == 0x3f800000u) flt = 1;
            else if (v > 1u) gt1 = 1;
        }
        if (tid == 0) { s_gt1 = 0u; s_flt = 0u; }
        __syncthreads();
        if (gt1) atomicOr(&s_gt1, 1u);
        if (flt) atomicOr(&s_flt, 1u);
        __syncthreads();
        const int mode = s_flt ? 2 : (s_gt1 ? 1 : 0);
        for (int i = tid; i < kB * kTE; i += 1024) {
            float val;
            if (mode == 2)      val = ((const float*)mask_raw)[i];
            else if (mode == 1) val = (float)(((const unsigned char*)mask_raw)[i]);
            else                val = (float)(((const int*)mask_raw)[i]);
            mask_f[i] = val;
        }
    }

    cg::this_grid().sync();

    // ======================= PHASE B ======================================
    const int b   = bx & 7;            // XCD-pinned batch
    const int t0  = (bx >> 3) * TM;
    const int s   = tid & 255;
    const int hq  = tid >> 8;          // 0..3 (128 h each)
    const int hqu = __builtin_amdgcn_readfirstlane(hq);

    // ---- score phase over this thread's 128-h quarter ----
    const float4* E4 = (const float4*)ewt + ((size_t)(b * 128 + hqu * 32) * 256 + s);
    const float4* Pb = (const float4*)(dwc + (size_t)(b * kTD + t0) * kH) + hqu * 32;
    const float4* V4 = (const float4*)V + hqu * 32;

    float a0 = 0.0f, a1 = 0.0f, a2 = 0.0f, a3 = 0.0f;
    #pragma unroll 4
    for (int g = 0; g < 32; ++g) {
        float4 e  = E4[(size_t)g * 256];
        float4 vv = V4[g];
        {   float4 q = Pb[g];
            float A_ = fmaf(e.x, q.x, 1.0f), B_ = fmaf(e.y, q.y, 1.0f);
            float C_ = fmaf(e.z, q.z, 1.0f), D_ = fmaf(e.w, q.w, 1.0f);
            float t1 = fmaf(vv.y, A_, vv.x * B_);
            float t2 = fmaf(vv.w, C_, vv.z * D_);
            float AB = A_ * B_, CD = C_ * D_;
            float num = fmaf(t2, AB, t1 * CD);
            a0 = fmaf(num, __builtin_amdgcn_rcpf(AB * CD), a0); }
        {   float4 q = Pb[128 + g];
            float A_ = fmaf(e.x, q.x, 1.0f), B_ = fmaf(e.y, q.y, 1.0f);
            float C_ = fmaf(e.z, q.z, 1.0f), D_ = fmaf(e.w, q.w, 1.0f);
            float t1 = fmaf(vv.y, A_, vv.x * B_);
            float t2 = fmaf(vv.w, C_, vv.z * D_);
            float AB = A_ * B_, CD = C_ * D_;
            float num = fmaf(t2, AB, t1 * CD);
            a1 = fmaf(num, __builtin_amdgcn_rcpf(AB * CD), a1); }
        {   float4 q = Pb[256 + g];
            float A_ = fmaf(e.x, q.x, 1.0f), B_ = fmaf(e.y, q.y, 1.0f);
            float C_ = fmaf(e.z, q.z, 1.0f), D_ = fmaf(e.w, q.w, 1.0f);
            float t1 = fmaf(vv.y, A_, vv.x * B_);
            float t2 = fmaf(vv.w, C_, vv.z * D_);
            float AB = A_ * B_, CD = C_ * D_;
            float num = fmaf(t2, AB, t1 * CD);
            a2 = fmaf(num, __builtin_amdgcn_rcpf(AB * CD), a2); }
        {   float4 q = Pb[384 + g];
            float A_ = fmaf(e.x, q.x, 1.0f), B_ = fmaf(e.y, q.y, 1.0f);
            float C_ = fmaf(e.z, q.z, 1.0f), D_ = fmaf(e.w, q.w, 1.0f);
            float t1 = fmaf(vv.y, A_, vv.x * B_);
            float t2 = fmaf(vv.w, C_, vv.z * D_);
            float AB = A_ * B_, CD = C_ * D_;
            float num = fmaf(t2, AB, t1 * CD);
            a3 = fmaf(num, __builtin_amdgcn_rcpf(AB * CD), a3); }
    }

    if (hq > 0) {
        float* pp = &smem.b.part[(hq - 1) * TM * kTE];
        pp[0 * kTE + s] = a0; pp[1 * kTE + s] = a1;
        pp[2 * kTE + s] = a2; pp[3 * kTE + s] = a3;
    }
    __syncthreads();

    const bool active = (hq == 0);
    const int wvq = s >> 6;
    float sc0, sc1, sc2, sc3;
    if (active) {
        const float* P = smem.b.part;
        const float pen = (1.0f - mask_f[b * kTE + s]) * -1e9f;
        sc0 = -2.0f * ((a0 + P[0 * TM * kTE + 0 * kTE + s]) +
                       (P[1 * TM * kTE + 0 * kTE + s] + P[2 * TM * kTE + 0 * kTE + s])) + pen;
        sc1 = -2.0f * ((a1 + P[0 * TM * kTE + 1 * kTE + s]) +
                       (P[1 * TM * kTE + 1 * kTE + s] + P[2 * TM * kTE + 1 * kTE + s])) + pen;
        sc2 = -2.0f * ((a2 + P[0 * TM * kTE + 2 * kTE + s]) +
                       (P[1 * TM * kTE + 2 * kTE + s] + P[2 * TM * kTE + 2 * kTE + s])) + pen;
        sc3 = -2.0f * ((a3 + P[0 * TM * kTE + 3 * kTE + s]) +
                       (P[1 * TM * kTE + 3 * kTE + s] + P[2 * TM * kTE + 3 * kTE + s])) + pen;
        float m0 = sc0, m1 = sc1, m2 = sc2, m3 = sc3;
        #pragma unroll
        for (int off = 1; off < 64; off <<= 1) {
            m0 = fmaxf(m0, __shfl_xor(m0, off));
            m1 = fmaxf(m1, __shfl_xor(m1, off));
            m2 = fmaxf(m2, __shfl_xor(m2, off));
            m3 = fmaxf(m3, __shfl_xor(m3, off));
        }
        if ((s & 63) == 0) {
            smem.b.red_mx[wvq][0] = m0; smem.b.red_mx[wvq][1] = m1;
            smem.b.red_mx[wvq][2] = m2; smem.b.red_mx[wvq][3] = m3;
        }
    }
    __syncthreads();

    float p0, p1, p2, p3;
    if (active) {
        const auto& R = smem.b.red_mx;
        float m0 = fmaxf(fmaxf(R[0][0], R[1][0]), fmaxf(R[2][0], R[3][0]));
        float m1 = fmaxf(fmaxf(R[0][1], R[1][1]), fmaxf(R[2][1], R[3][1]));
        float m2 = fmaxf(fmaxf(R[0][2], R[1][2]), fmaxf(R[2][2], R[3][2]));
        float m3 = fmaxf(fmaxf(R[0][3], R[1][3]), fmaxf(R[2][3], R[3][3]));
        p0 = __builtin_amdgcn_exp2f((sc0 - m0) * kLog2e);
        p1 = __builtin_amdgcn_exp2f((sc1 - m1) * kLog2e);
        p2 = __builtin_amdgcn_exp2f((sc2 - m2) * kLog2e);
        p3 = __builtin_amdgcn_exp2f((sc3 - m3) * kLog2e);
        float s0 = p0, s1 = p1, s2 = p2, s3 = p3;
        #pragma unroll
        for (int off = 1; off < 64; off <<= 1) {
            s0 += __shfl_xor(s0, off);
            s1 += __shfl_xor(s1, off);
            s2 += __shfl_xor(s2, off);
            s3 += __shfl_xor(s3, off);
        }
        if ((s & 63) == 0) {
            smem.b.red_sm[wvq][0] = s0; smem.b.red_sm[wvq][1] = s1;
            smem.b.red_sm[wvq][2] = s2; smem.b.red_sm[wvq][3] = s3;
        }
    }
    __syncthreads();

    if (active) {
        const auto& R = smem.b.red_sm;
        float s0 = (R[0][0] + R[1][0]) + (R[2][0] + R[3][0]);
        float s1 = (R[0][1] + R[1][1]) + (R[2][1] + R[3][1]);
        float s2 = (R[0][2] + R[1][2]) + (R[2][2] + R[3][2]);
        float s3 = (R[0][3] + R[1][3]) + (R[2][3] + R[3][3]);
        float4 w;
        w.x = p0 * __builtin_amdgcn_rcpf(s0);
        w.y = p1 * __builtin_amdgcn_rcpf(s1);
        w.z = p2 * __builtin_amdgcn_rcpf(s2);
        w.w = p3 * __builtin_amdgcn_rcpf(s3);
        smem.b.wgt4[s] = w;
        float* ao = attn_out + (size_t)(b * kTD + t0) * kTE + s;
        ao[0]       = w.x;
        ao[kTE]     = w.y;
        ao[2 * kTE] = w.z;
        ao[3 * kTE] = w.w;
    }
    __syncthreads();

    // ---- context phase: thread = (h-float4, s-octant); float4 loads ----
    const int th4 = tid & 127;           // h quad 0..127
    const int sq  = tid >> 7;            // s octant 0..7
    const float4* enc4 = (const float4*)(enc + (size_t)b * kTE * kH);
    float4 c[TM];
    #pragma unroll
    for (int t = 0; t < TM; ++t) c[t] = float4{0.f, 0.f, 0.f, 0.f};
    #pragma unroll 4
    for (int i = 0; i < 32; ++i) {
        const int ss = sq * 32 + i;
        float4 e = enc4[(size_t)ss * 128 + th4];
        float4 w = smem.b.wgt4[ss];
        c[0].x = fmaf(w.x, e.x, c[0].x); c[0].y = fmaf(w.x, e.y, c[0].y);
        c[0].z = fmaf(w.x, e.z, c[0].z); c[0].w = fmaf(w.x, e.w, c[0].w);
        c[1].x = fmaf(w.y, e.x, c[1].x); c[1].y = fmaf(w.y, e.y, c[1].y);
        c[1].z = fmaf(w.y, e.z, c[1].z); c[1].w = fmaf(w.y, e.w, c[1].w);
        c[2].x = fmaf(w.z, e.x, c[2].x); c[2].y = fmaf(w.z, e.y, c[2].y);
        c[2].z = fmaf(w.z, e.z, c[2].z); c[2].w = fmaf(w.z, e.w, c[2].w);
        c[3].x = fmaf(w.w, e.x, c[3].x); c[3].y = fmaf(w.w, e.y, c[3].y);
        c[3].z = fmaf(w.w, e.z, c[3].z); c[3].w = fmaf(w.w, e.w, c[3].w);
    }
    // tree combine: 8 -> 4 -> 1
    if (sq >= 4) {
        #pragma unroll
        for (int t = 0; t < TM; ++t) smem.b.pctx[sq - 4][t][th4] = c[t];
    }
    __syncthreads();
    if (sq < 4) {
        #pragma unroll
        for (int t = 0; t < TM; ++t) {
            float4 p = smem.b.pctx[sq][t][th4];
            c[t].x += p.x; c[t].y += p.y; c[t].z += p.z; c[t].w += p.w;
        }
    }
    __syncthreads();
    if (sq >= 1 && sq < 4) {
        #pragma unroll
        for (int t = 0; t < TM; ++t) smem.b.pctx[sq - 1][t][th4] = c[t];
    }
    __syncthreads();
    if (sq == 0) {
        #pragma unroll
        for (int t = 0; t < TM; ++t) {
            float4 p0v = smem.b.pctx[0][t][th4];
            float4 p1v = smem.b.pctx[1][t][th4];
            float4 p2v = smem.b.pctx[2][t][th4];
            c[t].x += (p0v.x + p1v.x) + p2v.x;
            c[t].y += (p0v.y + p1v.y) + p2v.y;
            c[t].z += (p0v.z + p1v.z) + p2v.z;
            c[t].w += (p0v.w + p1v.w) + p2v.w;
            *(float4*)&ctx_out[(size_t)(b * kTD + t0 + t) * kH + th4 * 4] = c[t];
        }
    }
}

// ---------------------------------------------------------------------------
extern "C" void kernel_launch(void* const* d_in, const int* in_sizes, int n_in,
                              void* d_out, int out_size, void* d_ws, size_t ws_size,
                              hipStream_t stream) {
    const float* enc  = (const float*)d_in[0];   // [B, TE, H]
    const float* dec  = (const float*)d_in[1];   // [B, TD, H]
    const void*  mask = d_in[2];                 // [B, TE] bool
    const float* W1   = (const float*)d_in[3];
    const float* W2   = (const float*)d_in[4];
    const float* V    = (const float*)d_in[5];   // [H, 1]

    float* ctx_out  = (float*)d_out;                     // [B, TD, H]
    float* attn_out = (float*)d_out + kB * kTD * kH;     // [B, TD, TE]

    char* ws = (char*)d_ws;
    float* mask_f = (float*)ws;                                      // 2048 f
    float* ewt    = (float*)(ws + 8192);                             // E^T packed [b][h/4][s][4]
    float* dwc    = (float*)(ws + 8192 + (size_t)kB * kTE * kH * 4); // P[t][h]

    void* args[] = { (void*)&enc, (void*)&dec, (void*)&W1, (void*)&W2,
                     (void*)&mask, (void*)&V, (void*)&ewt, (void*)&dwc,
                     (void*)&mask_f, (void*)&ctx_out, (void*)&attn_out };
    hipLaunchCooperativeKernel((void*)mega_kernel, dim3(256), dim3(1024),
                               args, 0, stream);
}

// Round 7
// 57.734 us; speedup vs baseline: 1.7708x; 1.7708x over previous
//
#include <hip/hip_runtime.h>
#include <hip/hip_bf16.h>
#include <math.h>

// Problem constants
constexpr int kB  = 8;
constexpr int kTD = 128;
constexpr int kTE = 256;
constexpr int kH  = 512;

constexpr float kTwoLog2e = 2.8853900817779268f; // 2*log2(e)
constexpr float kLog2e    = 1.4426950408889634f;

constexpr int TM = 4;              // t-tile in fused kernel
constexpr int GEMM_BLOCKS = 384;   // 48 m-tiles (32 enc + 16 dec) x 8 n-tiles

typedef __attribute__((ext_vector_type(8)))  short short8;   // 8 bf16 (4 VGPRs)
typedef __attribute__((ext_vector_type(16))) float f32x16;   // 32x32 acc

// round-to-nearest-even f32 -> bf16 (bit manip; no NaN inputs here)
__device__ __forceinline__ unsigned short f2bf(float x) {
    unsigned int u = __float_as_uint(x);
    return (unsigned short)((u + 0x7fffu + ((u >> 16) & 1u)) >> 16);
}
__device__ __forceinline__ float bf2f(unsigned short h) {
    return __uint_as_float(((unsigned int)h) << 16);
}

// ---------------------------------------------------------------------------
// Kernel 1 (prep): both GEMMs via split-bf16 MFMA (Ahi*Whi + Ahi*Wlo + Alo*Whi)
// 64x64 tile per 256-thread block (4 waves, 2x2 of 32x32), BK=32.
// Epilogue: C -> exp2(2*log2e*C).
//   enc rows (m < 2048): packed-transposed store ewt[b][h>>2][s][h&3]
//   dec rows (m >= 2048): row-major dwc[t][h]
// (verbatim round-5 structure — proven correct & conflict-free)
// ---------------------------------------------------------------------------
__global__ __launch_bounds__(256)
void prep_kernel(const float* __restrict__ enc, const float* __restrict__ dec,
                 const float* __restrict__ W1, const float* __restrict__ W2,
                 const void* __restrict__ mask_raw,
                 float* __restrict__ ewt, float* __restrict__ dwc,
                 float* __restrict__ mask_f) {
    const int bx = blockIdx.x;
    const int tid = threadIdx.x;

    if (bx == GEMM_BLOCKS) {
        // ---- mask decode (layout auto-detect: int32 / byte / float) ----
        const unsigned int* w = (const unsigned int*)mask_raw;
        unsigned int gt1 = 0, flt = 0;
        for (int i = tid; i < 512; i += 256) {      // first 2048B safe everywhere
            unsigned int v = w[i];
            if (v == 0x3f800000u) flt = 1;
            else if (v > 1u) gt1 = 1;
        }
        __shared__ unsigned int s_gt1, s_flt;
        if (tid == 0) { s_gt1 = 0u; s_flt = 0u; }
        __syncthreads();
        if (gt1) atomicOr(&s_gt1, 1u);
        if (flt) atomicOr(&s_flt, 1u);
        __syncthreads();
        const int mode = s_flt ? 2 : (s_gt1 ? 1 : 0);
        for (int i = tid; i < kB * kTE; i += 256) {
            float val;
            if (mode == 2)      val = ((const float*)mask_raw)[i];
            else if (mode == 1) val = (float)(((const unsigned char*)mask_raw)[i]);
            else                val = (float)(((const int*)mask_raw)[i]);
            mask_f[i] = val;
        }
        return;
    }

    const int mt = bx >> 3;            // 0..47 m-tile
    const int nt = bx & 7;             // 0..7  n-tile
    const bool is_enc = (mt < 32);
    const int m0 = mt * 64;            // global row (enc rows 0..2047, dec 2048..)
    const int n0 = nt * 64;
    const float* Abase = is_enc ? (enc + (size_t)m0 * kH)
                                : (dec + (size_t)(m0 - 2048) * kH);
    const float* W = is_enc ? W1 : W2;

    // LDS: bf16 hi/lo tiles (pitch 40 ushorts = 80B, 16B aligned, low-conflict)
    __shared__ __align__(16) unsigned short Ahi[64][40], Alo[64][40];
    __shared__ __align__(16) unsigned short Bhi[64][40], Blo[64][40];
    __shared__ float Ws[32][68];       // fp32 W-tile for in-LDS transpose

    const int lane = tid & 63;
    const int wv   = tid >> 6;         // 4 waves
    const int wr   = wv >> 1, wc = wv & 1;
    const int col  = lane & 31, hi5 = lane >> 5;

    // staging roles
    const int ar  = tid >> 2;          // A: row 0..63
    const int akc = (tid & 3) * 8;     // A: k-chunk of 8
    const int wkr = tid >> 3;          // W pass1: k-row 0..31
    const int wnc = (tid & 7) * 8;     // W pass1: n-chunk of 8
    const int pn  = tid & 63;          // W pass2: n 0..63 (lane-consecutive!)
    const int pkc = (tid >> 6) * 8;    // W pass2: k-chunk of 8

    f32x16 acc = {};

    // preload step 0
    float4 a0p = *(const float4*)&Abase[(size_t)ar * kH + akc];
    float4 a1p = *(const float4*)&Abase[(size_t)ar * kH + akc + 4];
    float4 w0p = *(const float4*)&W[(size_t)wkr * kH + n0 + wnc];
    float4 w1p = *(const float4*)&W[(size_t)wkr * kH + n0 + wnc + 4];

    for (int step = 0; step < 16; ++step) {
        // ---- stage W fp32 (pass1) + A hi/lo ----
        *(float4*)&Ws[wkr][wnc]     = w0p;
        *(float4*)&Ws[wkr][wnc + 4] = w1p;
        {
            uint4 H, L;
            float f[8] = {a0p.x, a0p.y, a0p.z, a0p.w, a1p.x, a1p.y, a1p.z, a1p.w};
            unsigned short hs[8], ls[8];
            #pragma unroll
            for (int j = 0; j < 8; ++j) {
                hs[j] = f2bf(f[j]);
                ls[j] = f2bf(f[j] - bf2f(hs[j]));
            }
            H.x = hs[0] | (hs[1] << 16); H.y = hs[2] | (hs[3] << 16);
            H.z = hs[4] | (hs[5] << 16); H.w = hs[6] | (hs[7] << 16);
            L.x = ls[0] | (ls[1] << 16); L.y = ls[2] | (ls[3] << 16);
            L.z = ls[4] | (ls[5] << 16); L.w = ls[6] | (ls[7] << 16);
            *(uint4*)&Ahi[ar][akc] = H;
            *(uint4*)&Alo[ar][akc] = L;
        }
        __syncthreads();

        // ---- W pass2: transpose-read columns, split, store K-major ----
        {
            uint4 H, L;
            unsigned short hs[8], ls[8];
            #pragma unroll
            for (int j = 0; j < 8; ++j) {
                float x = Ws[pkc + j][pn];
                hs[j] = f2bf(x);
                ls[j] = f2bf(x - bf2f(hs[j]));
            }
            H.x = hs[0] | (hs[1] << 16); H.y = hs[2] | (hs[3] << 16);
            H.z = hs[4] | (hs[5] << 16); H.w = hs[6] | (hs[7] << 16);
            L.x = ls[0] | (ls[1] << 16); L.y = ls[2] | (ls[3] << 16);
            L.z = ls[4] | (ls[5] << 16); L.w = ls[6] | (ls[7] << 16);
            *(uint4*)&Bhi[pn][pkc] = H;
            *(uint4*)&Blo[pn][pkc] = L;
        }

        // prefetch next step's globals (land during MFMA phase)
        if (step < 15) {
            const int k1 = (step + 1) * 32;
            a0p = *(const float4*)&Abase[(size_t)ar * kH + k1 + akc];
            a1p = *(const float4*)&Abase[(size_t)ar * kH + k1 + akc + 4];
            w0p = *(const float4*)&W[(size_t)(k1 + wkr) * kH + n0 + wnc];
            w1p = *(const float4*)&W[(size_t)(k1 + wkr) * kH + n0 + wnc + 4];
        }
        __syncthreads();

        // ---- fragments + MFMA: 2 k-chunks x 3 split-products ----
        #pragma unroll
        for (int kc = 0; kc < 32; kc += 16) {
            const int ka = kc + hi5 * 8;
            short8 ah = *(const short8*)&Ahi[wr * 32 + col][ka];
            short8 al = *(const short8*)&Alo[wr * 32 + col][ka];
            short8 bh = *(const short8*)&Bhi[wc * 32 + col][ka];
            short8 bl = *(const short8*)&Blo[wc * 32 + col][ka];
            acc = __builtin_amdgcn_mfma_f32_32x32x16_bf16(ah, bh, acc, 0, 0, 0);
            acc = __builtin_amdgcn_mfma_f32_32x32x16_bf16(ah, bl, acc, 0, 0, 0);
            acc = __builtin_amdgcn_mfma_f32_32x32x16_bf16(al, bh, acc, 0, 0, 0);
        }
        __syncthreads();
    }

    // ---- epilogue: exp2 + store ----
    const int h = n0 + wc * 32 + col;
    if (is_enc) {
        #pragma unroll
        for (int reg = 0; reg < 16; ++reg) {
            const int row = (reg & 3) + 8 * (reg >> 2) + 4 * hi5;
            const int gm = m0 + wr * 32 + row;            // = b*256 + s
            const int bb = gm >> 8, sE = gm & 255;
            float val = __builtin_amdgcn_exp2f(acc[reg] * kTwoLog2e);
            ewt[(((size_t)bb * 128 + (h >> 2)) * 256 + sE) * 4 + (h & 3)] = val;
        }
    } else {
        #pragma unroll
        for (int reg = 0; reg < 16; ++reg) {
            const int row = (reg & 3) + 8 * (reg >> 2) + 4 * hi5;
            const int dm = (m0 - 2048) + wr * 32 + row;   // = b*128 + t
            float val = __builtin_amdgcn_exp2f(acc[reg] * kTwoLog2e);
            dwc[(size_t)dm * kH + h] = val;
        }
    }
}

// ---------------------------------------------------------------------------
// Kernel 2 (fused): scores -> softmax -> context, one (b, 4-t tile) per block.
//   1024 threads: s = tid&255, hq = tid>>8 (128-h quarter).
//   P (4 rows) + V staged in LDS (wave-uniform ds_read_b128 broadcasts);
//   E streamed from global with EXPLICIT depth-4 register prefetch
//   (deliberate benign over-read of <=16KB into the adjacent dwc ws region).
//   tanh(ew+dw) = 1 - 2/(E*P+1); 4-way rcp pairing; SV constant cancels.
// ---------------------------------------------------------------------------
__global__ __launch_bounds__(1024)
void fused_attn_kernel(const float* __restrict__ ewt, const float* __restrict__ dwc,
                       const float* __restrict__ enc, const float* __restrict__ V,
                       const float* __restrict__ mask_f,
                       float* __restrict__ ctx_out, float* __restrict__ attn_out) {
    const int bid = blockIdx.x;
    const int b   = bid & 7;            // XCD-pinned batch
    const int t0  = (bid >> 3) * TM;
    const int tid = threadIdx.x;
    const int s   = tid & 255;
    const int hq  = tid >> 8;           // 0..3

    __shared__ float p_s[TM * kH];      // 8KB  pre-exponentiated P rows
    __shared__ float v_s[kH];           // 2KB
    __shared__ union {
        float  part[3 * TM * kTE];      // 12KB score partials
        float4 pctx[4][TM][128];        // 32KB context partial tree
    } u;
    __shared__ float4 wgt4[kTE];        // 4KB softmax weights, t-major
    __shared__ float red_mx[4][TM], red_sm[4][TM];

    // stage P (4 rows) and V
    if (tid < 512)
        ((float4*)p_s)[tid] =
            ((const float4*)(dwc + (size_t)(b * kTD + t0) * kH))[tid];
    else if (tid < 640)
        ((float4*)v_s)[tid - 512] = ((const float4*)V)[tid - 512];
    __syncthreads();

    // ---- score phase over this thread's 128-h quarter ----
    const float4* E4 = (const float4*)ewt + ((size_t)(b * 128 + hq * 32) * 256 + s);
    const float4* Pq = (const float4*)p_s;   // [t*128 + g]
    const float4* Vq = (const float4*)v_s;
    const int gb = hq * 32;

    float a0 = 0.0f, a1 = 0.0f, a2 = 0.0f, a3 = 0.0f;
    float4 e0 = E4[0], e1 = E4[256], e2 = E4[512], e3 = E4[768];

#define SCORE_T(eV, gg, qt, accv)                                          \
    {   float4 q = Pq[(qt) * 128 + gb + (gg)];                             \
        float A_ = fmaf(eV.x, q.x, 1.0f), B_ = fmaf(eV.y, q.y, 1.0f);      \
        float C_ = fmaf(eV.z, q.z, 1.0f), D_ = fmaf(eV.w, q.w, 1.0f);      \
        float t1 = fmaf(vv.y, A_, vv.x * B_);                              \
        float t2 = fmaf(vv.w, C_, vv.z * D_);                              \
        float AB = A_ * B_, CD = C_ * D_;                                  \
        accv = fmaf(fmaf(t2, AB, t1 * CD),                                 \
                    __builtin_amdgcn_rcpf(AB * CD), accv); }
#define SCORE_STEP(eV, gg)                                                 \
    {   float4 vv = Vq[gb + (gg)];                                         \
        SCORE_T(eV, gg, 0, a0) SCORE_T(eV, gg, 1, a1)                      \
        SCORE_T(eV, gg, 2, a2) SCORE_T(eV, gg, 3, a3) }

    #pragma unroll
    for (int g = 0; g < 32; g += 4) {
        // prefetch next group (last group reads ~<=16KB past ewt into dwc: benign)
        float4 f0 = E4[(size_t)(g + 4) * 256];
        float4 f1 = E4[(size_t)(g + 5) * 256];
        float4 f2 = E4[(size_t)(g + 6) * 256];
        float4 f3 = E4[(size_t)(g + 7) * 256];
        SCORE_STEP(e0, g)     SCORE_STEP(e1, g + 1)
        SCORE_STEP(e2, g + 2) SCORE_STEP(e3, g + 3)
        e0 = f0; e1 = f1; e2 = f2; e3 = f3;
    }
#undef SCORE_STEP
#undef SCORE_T

    if (hq > 0) {
        float* pp = &u.part[(hq - 1) * TM * kTE];
        pp[0 * kTE + s] = a0; pp[1 * kTE + s] = a1;
        pp[2 * kTE + s] = a2; pp[3 * kTE + s] = a3;
    }
    __syncthreads();

    const bool active = (hq == 0);
    const int wvq = s >> 6;
    float sc0, sc1, sc2, sc3;
    if (active) {
        const float* P = u.part;
        const float pen = (1.0f - mask_f[b * kTE + s]) * -1e9f;
        sc0 = -2.0f * ((a0 + P[0 * TM * kTE + 0 * kTE + s]) +
                       (P[1 * TM * kTE + 0 * kTE + s] + P[2 * TM * kTE + 0 * kTE + s])) + pen;
        sc1 = -2.0f * ((a1 + P[0 * TM * kTE + 1 * kTE + s]) +
                       (P[1 * TM * kTE + 1 * kTE + s] + P[2 * TM * kTE + 1 * kTE + s])) + pen;
        sc2 = -2.0f * ((a2 + P[0 * TM * kTE + 2 * kTE + s]) +
                       (P[1 * TM * kTE + 2 * kTE + s] + P[2 * TM * kTE + 2 * kTE + s])) + pen;
        sc3 = -2.0f * ((a3 + P[0 * TM * kTE + 3 * kTE + s]) +
                       (P[1 * TM * kTE + 3 * kTE + s] + P[2 * TM * kTE + 3 * kTE + s])) + pen;
        float m0 = sc0, m1 = sc1, m2 = sc2, m3 = sc3;
        #pragma unroll
        for (int off = 1; off < 64; off <<= 1) {
            m0 = fmaxf(m0, __shfl_xor(m0, off));
            m1 = fmaxf(m1, __shfl_xor(m1, off));
            m2 = fmaxf(m2, __shfl_xor(m2, off));
            m3 = fmaxf(m3, __shfl_xor(m3, off));
        }
        if ((s & 63) == 0) {
            red_mx[wvq][0] = m0; red_mx[wvq][1] = m1;
            red_mx[wvq][2] = m2; red_mx[wvq][3] = m3;
        }
    }
    __syncthreads();

    float p0, p1, p2, p3;
    if (active) {
        float m0 = fmaxf(fmaxf(red_mx[0][0], red_mx[1][0]), fmaxf(red_mx[2][0], red_mx[3][0]));
        float m1 = fmaxf(fmaxf(red_mx[0][1], red_mx[1][1]), fmaxf(red_mx[2][1], red_mx[3][1]));
        float m2 = fmaxf(fmaxf(red_mx[0][2], red_mx[1][2]), fmaxf(red_mx[2][2], red_mx[3][2]));
        float m3 = fmaxf(fmaxf(red_mx[0][3], red_mx[1][3]), fmaxf(red_mx[2][3], red_mx[3][3]));
        p0 = __builtin_amdgcn_exp2f((sc0 - m0) * kLog2e);
        p1 = __builtin_amdgcn_exp2f((sc1 - m1) * kLog2e);
        p2 = __builtin_amdgcn_exp2f((sc2 - m2) * kLog2e);
        p3 = __builtin_amdgcn_exp2f((sc3 - m3) * kLog2e);
        float s0 = p0, s1 = p1, s2 = p2, s3 = p3;
        #pragma unroll
        for (int off = 1; off < 64; off <<= 1) {
            s0 += __shfl_xor(s0, off);
            s1 += __shfl_xor(s1, off);
            s2 += __shfl_xor(s2, off);
            s3 += __shfl_xor(s3, off);
        }
        if ((s & 63) == 0) {
            red_sm[wvq][0] = s0; red_sm[wvq][1] = s1;
            red_sm[wvq][2] = s2; red_sm[wvq][3] = s3;
        }
    }
    __syncthreads();

    if (active) {
        float s0 = (red_sm[0][0] + red_sm[1][0]) + (red_sm[2][0] + red_sm[3][0]);
        float s1 = (red_sm[0][1] + red_sm[1][1]) + (red_sm[2][1] + red_sm[3][1]);
        float s2 = (red_sm[0][2] + red_sm[1][2]) + (red_sm[2][2] + red_sm[3][2]);
        float s3 = (red_sm[0][3] + red_sm[1][3]) + (red_sm[2][3] + red_sm[3][3]);
        float4 w;
        w.x = p0 * __builtin_amdgcn_rcpf(s0);
        w.y = p1 * __builtin_amdgcn_rcpf(s1);
        w.z = p2 * __builtin_amdgcn_rcpf(s2);
        w.w = p3 * __builtin_amdgcn_rcpf(s3);
        wgt4[s] = w;
        float* ao = attn_out + (size_t)(b * kTD + t0) * kTE + s;
        ao[0]       = w.x;
        ao[kTE]     = w.y;
        ao[2 * kTE] = w.z;
        ao[3 * kTE] = w.w;
    }
    __syncthreads();

    // ---- context phase: thread = (h-float4, s-octant); float4 loads ----
    const int th4 = tid & 127;           // h quad 0..127
    const int sq  = tid >> 7;            // s octant 0..7
    const float4* enc4 = (const float4*)(enc + (size_t)b * kTE * kH);
    float4 c[TM];
    #pragma unroll
    for (int t = 0; t < TM; ++t) c[t] = float4{0.f, 0.f, 0.f, 0.f};
    #pragma unroll 8
    for (int i = 0; i < 32; ++i) {
        const int ss = sq * 32 + i;
        float4 e = enc4[(size_t)ss * 128 + th4];
        float4 w = wgt4[ss];
        c[0].x = fmaf(w.x, e.x, c[0].x); c[0].y = fmaf(w.x, e.y, c[0].y);
        c[0].z = fmaf(w.x, e.z, c[0].z); c[0].w = fmaf(w.x, e.w, c[0].w);
        c[1].x = fmaf(w.y, e.x, c[1].x); c[1].y = fmaf(w.y, e.y, c[1].y);
        c[1].z = fmaf(w.y, e.z, c[1].z); c[1].w = fmaf(w.y, e.w, c[1].w);
        c[2].x = fmaf(w.z, e.x, c[2].x); c[2].y = fmaf(w.z, e.y, c[2].y);
        c[2].z = fmaf(w.z, e.z, c[2].z); c[2].w = fmaf(w.z, e.w, c[2].w);
        c[3].x = fmaf(w.w, e.x, c[3].x); c[3].y = fmaf(w.w, e.y, c[3].y);
        c[3].z = fmaf(w.w, e.z, c[3].z); c[3].w = fmaf(w.w, e.w, c[3].w);
    }
    // tree combine: 8 -> 4 -> 1
    if (sq >= 4) {
        #pragma unroll
        for (int t = 0; t < TM; ++t) u.pctx[sq - 4][t][th4] = c[t];
    }
    __syncthreads();
    if (sq < 4) {
        #pragma unroll
        for (int t = 0; t < TM; ++t) {
            float4 p = u.pctx[sq][t][th4];
            c[t].x += p.x; c[t].y += p.y; c[t].z += p.z; c[t].w += p.w;
        }
    }
    __syncthreads();
    if (sq >= 1 && sq < 4) {
        #pragma unroll
        for (int t = 0; t < TM; ++t) u.pctx[sq - 1][t][th4] = c[t];
    }
    __syncthreads();
    if (sq == 0) {
        #pragma unroll
        for (int t = 0; t < TM; ++t) {
            float4 q0v = u.pctx[0][t][th4];
            float4 q1v = u.pctx[1][t][th4];
            float4 q2v = u.pctx[2][t][th4];
            c[t].x += (q0v.x + q1v.x) + q2v.x;
            c[t].y += (q0v.y + q1v.y) + q2v.y;
            c[t].z += (q0v.z + q1v.z) + q2v.z;
            c[t].w += (q0v.w + q1v.w) + q2v.w;
            *(float4*)&ctx_out[(size_t)(b * kTD + t0 + t) * kH + th4 * 4] = c[t];
        }
    }
}

// ---------------------------------------------------------------------------
extern "C" void kernel_launch(void* const* d_in, const int* in_sizes, int n_in,
                              void* d_out, int out_size, void* d_ws, size_t ws_size,
                              hipStream_t stream) {
    const float* enc  = (const float*)d_in[0];   // [B, TE, H]
    const float* dec  = (const float*)d_in[1];   // [B, TD, H]
    const void*  mask = d_in[2];                 // [B, TE] bool
    const float* W1   = (const float*)d_in[3];
    const float* W2   = (const float*)d_in[4];
    const float* V    = (const float*)d_in[5];   // [H, 1]

    float* ctx_out  = (float*)d_out;                     // [B, TD, H]
    float* attn_out = (float*)d_out + kB * kTD * kH;     // [B, TD, TE]

    char* ws = (char*)d_ws;
    float* mask_f = (float*)ws;                                      // 2048 f
    float* ewt    = (float*)(ws + 8192);                             // E^T packed [b][h/4][s][4]
    float* dwc    = (float*)(ws + 8192 + (size_t)kB * kTE * kH * 4); // P[t][h]

    hipLaunchKernelGGL(prep_kernel, dim3(GEMM_BLOCKS + 1), dim3(256), 0, stream,
                       enc, dec, W1, W2, mask, ewt, dwc, mask_f);
    hipLaunchKernelGGL(fused_attn_kernel, dim3(kB * kTD / TM), dim3(1024), 0, stream,
                       ewt, dwc, enc, V, mask_f, ctx_out, attn_out);
}

// Round 8
// 43.870 us; speedup vs baseline: 2.3304x; 1.3160x over previous
//
#include <hip/hip_runtime.h>
#include <hip/hip_bf16.h>
#include <math.h>

// Problem constants
constexpr int kB  = 8;
constexpr int kTD = 128;
constexpr int kTE = 256;
constexpr int kH  = 512;

constexpr float kTwoLog2e = 2.8853900817779268f; // 2*log2(e)
constexpr float kLog2e    = 1.4426950408889634f;

constexpr int TM = 4;              // t-tile in fused kernel
constexpr int GEMM_BLOCKS = 384;   // 48 m-tiles (32 enc + 16 dec) x 8 n-tiles

typedef __attribute__((ext_vector_type(8)))  short short8;   // 8 bf16 (4 VGPRs)
typedef __attribute__((ext_vector_type(16))) float f32x16;   // 32x32 acc

// round-to-nearest-even f32 -> bf16 (bit manip; no NaN inputs here)
__device__ __forceinline__ unsigned short f2bf(float x) {
    unsigned int u = __float_as_uint(x);
    return (unsigned short)((u + 0x7fffu + ((u >> 16) & 1u)) >> 16);
}
__device__ __forceinline__ float bf2f(unsigned short h) {
    return __uint_as_float(((unsigned int)h) << 16);
}

// ---------------------------------------------------------------------------
// Kernel 1 (prep): both GEMMs via split-bf16 MFMA (Ahi*Whi + Ahi*Wlo + Alo*Whi)
// 64x64 tile per 256-thread block (4 waves, 2x2 of 32x32), BK=32.
// Epilogue: C -> exp2(2*log2e*C).
//   enc rows (m < 2048): packed-transposed store ewt[b][h>>2][s][h&3]
//   dec rows (m >= 2048): row-major dwc[t][h]
// (verbatim round-5 structure — proven correct & conflict-free)
// ---------------------------------------------------------------------------
__global__ __launch_bounds__(256)
void prep_kernel(const float* __restrict__ enc, const float* __restrict__ dec,
                 const float* __restrict__ W1, const float* __restrict__ W2,
                 const void* __restrict__ mask_raw,
                 float* __restrict__ ewt, float* __restrict__ dwc,
                 float* __restrict__ mask_f) {
    const int bx = blockIdx.x;
    const int tid = threadIdx.x;

    if (bx == GEMM_BLOCKS) {
        // ---- mask decode (layout auto-detect: int32 / byte / float) ----
        const unsigned int* w = (const unsigned int*)mask_raw;
        unsigned int gt1 = 0, flt = 0;
        for (int i = tid; i < 512; i += 256) {      // first 2048B safe everywhere
            unsigned int v = w[i];
            if (v == 0x3f800000u) flt = 1;
            else if (v > 1u) gt1 = 1;
        }
        __shared__ unsigned int s_gt1, s_flt;
        if (tid == 0) { s_gt1 = 0u; s_flt = 0u; }
        __syncthreads();
        if (gt1) atomicOr(&s_gt1, 1u);
        if (flt) atomicOr(&s_flt, 1u);
        __syncthreads();
        const int mode = s_flt ? 2 : (s_gt1 ? 1 : 0);
        for (int i = tid; i < kB * kTE; i += 256) {
            float val;
            if (mode == 2)      val = ((const float*)mask_raw)[i];
            else if (mode == 1) val = (float)(((const unsigned char*)mask_raw)[i]);
            else                val = (float)(((const int*)mask_raw)[i]);
            mask_f[i] = val;
        }
        return;
    }

    const int mt = bx >> 3;            // 0..47 m-tile
    const int nt = bx & 7;             // 0..7  n-tile
    const bool is_enc = (mt < 32);
    const int m0 = mt * 64;            // global row (enc rows 0..2047, dec 2048..)
    const int n0 = nt * 64;
    const float* Abase = is_enc ? (enc + (size_t)m0 * kH)
                                : (dec + (size_t)(m0 - 2048) * kH);
    const float* W = is_enc ? W1 : W2;

    // LDS: bf16 hi/lo tiles (pitch 40 ushorts = 80B, 16B aligned, low-conflict)
    __shared__ __align__(16) unsigned short Ahi[64][40], Alo[64][40];
    __shared__ __align__(16) unsigned short Bhi[64][40], Blo[64][40];
    __shared__ float Ws[32][68];       // fp32 W-tile for in-LDS transpose

    const int lane = tid & 63;
    const int wv   = tid >> 6;         // 4 waves
    const int wr   = wv >> 1, wc = wv & 1;
    const int col  = lane & 31, hi5 = lane >> 5;

    // staging roles
    const int ar  = tid >> 2;          // A: row 0..63
    const int akc = (tid & 3) * 8;     // A: k-chunk of 8
    const int wkr = tid >> 3;          // W pass1: k-row 0..31
    const int wnc = (tid & 7) * 8;     // W pass1: n-chunk of 8
    const int pn  = tid & 63;          // W pass2: n 0..63 (lane-consecutive!)
    const int pkc = (tid >> 6) * 8;    // W pass2: k-chunk of 8

    f32x16 acc = {};

    // preload step 0
    float4 a0p = *(const float4*)&Abase[(size_t)ar * kH + akc];
    float4 a1p = *(const float4*)&Abase[(size_t)ar * kH + akc + 4];
    float4 w0p = *(const float4*)&W[(size_t)wkr * kH + n0 + wnc];
    float4 w1p = *(const float4*)&W[(size_t)wkr * kH + n0 + wnc + 4];

    for (int step = 0; step < 16; ++step) {
        // ---- stage W fp32 (pass1) + A hi/lo ----
        *(float4*)&Ws[wkr][wnc]     = w0p;
        *(float4*)&Ws[wkr][wnc + 4] = w1p;
        {
            uint4 H, L;
            float f[8] = {a0p.x, a0p.y, a0p.z, a0p.w, a1p.x, a1p.y, a1p.z, a1p.w};
            unsigned short hs[8], ls[8];
            #pragma unroll
            for (int j = 0; j < 8; ++j) {
                hs[j] = f2bf(f[j]);
                ls[j] = f2bf(f[j] - bf2f(hs[j]));
            }
            H.x = hs[0] | (hs[1] << 16); H.y = hs[2] | (hs[3] << 16);
            H.z = hs[4] | (hs[5] << 16); H.w = hs[6] | (hs[7] << 16);
            L.x = ls[0] | (ls[1] << 16); L.y = ls[2] | (ls[3] << 16);
            L.z = ls[4] | (ls[5] << 16); L.w = ls[6] | (ls[7] << 16);
            *(uint4*)&Ahi[ar][akc] = H;
            *(uint4*)&Alo[ar][akc] = L;
        }
        __syncthreads();

        // ---- W pass2: transpose-read columns, split, store K-major ----
        {
            uint4 H, L;
            unsigned short hs[8], ls[8];
            #pragma unroll
            for (int j = 0; j < 8; ++j) {
                float x = Ws[pkc + j][pn];
                hs[j] = f2bf(x);
                ls[j] = f2bf(x - bf2f(hs[j]));
            }
            H.x = hs[0] | (hs[1] << 16); H.y = hs[2] | (hs[3] << 16);
            H.z = hs[4] | (hs[5] << 16); H.w = hs[6] | (hs[7] << 16);
            L.x = ls[0] | (ls[1] << 16); L.y = ls[2] | (ls[3] << 16);
            L.z = ls[4] | (ls[5] << 16); L.w = ls[6] | (ls[7] << 16);
            *(uint4*)&Bhi[pn][pkc] = H;
            *(uint4*)&Blo[pn][pkc] = L;
        }

        // prefetch next step's globals (land during MFMA phase)
        if (step < 15) {
            const int k1 = (step + 1) * 32;
            a0p = *(const float4*)&Abase[(size_t)ar * kH + k1 + akc];
            a1p = *(const float4*)&Abase[(size_t)ar * kH + k1 + akc + 4];
            w0p = *(const float4*)&W[(size_t)(k1 + wkr) * kH + n0 + wnc];
            w1p = *(const float4*)&W[(size_t)(k1 + wkr) * kH + n0 + wnc + 4];
        }
        __syncthreads();

        // ---- fragments + MFMA: 2 k-chunks x 3 split-products ----
        #pragma unroll
        for (int kc = 0; kc < 32; kc += 16) {
            const int ka = kc + hi5 * 8;
            short8 ah = *(const short8*)&Ahi[wr * 32 + col][ka];
            short8 al = *(const short8*)&Alo[wr * 32 + col][ka];
            short8 bh = *(const short8*)&Bhi[wc * 32 + col][ka];
            short8 bl = *(const short8*)&Blo[wc * 32 + col][ka];
            acc = __builtin_amdgcn_mfma_f32_32x32x16_bf16(ah, bh, acc, 0, 0, 0);
            acc = __builtin_amdgcn_mfma_f32_32x32x16_bf16(ah, bl, acc, 0, 0, 0);
            acc = __builtin_amdgcn_mfma_f32_32x32x16_bf16(al, bh, acc, 0, 0, 0);
        }
        __syncthreads();
    }

    // ---- epilogue: exp2 + store ----
    const int h = n0 + wc * 32 + col;
    if (is_enc) {
        #pragma unroll
        for (int reg = 0; reg < 16; ++reg) {
            const int row = (reg & 3) + 8 * (reg >> 2) + 4 * hi5;
            const int gm = m0 + wr * 32 + row;            // = b*256 + s
            const int bb = gm >> 8, sE = gm & 255;
            float val = __builtin_amdgcn_exp2f(acc[reg] * kTwoLog2e);
            ewt[(((size_t)bb * 128 + (h >> 2)) * 256 + sE) * 4 + (h & 3)] = val;
        }
    } else {
        #pragma unroll
        for (int reg = 0; reg < 16; ++reg) {
            const int row = (reg & 3) + 8 * (reg >> 2) + 4 * hi5;
            const int dm = (m0 - 2048) + wr * 32 + row;   // = b*128 + t
            float val = __builtin_amdgcn_exp2f(acc[reg] * kTwoLog2e);
            dwc[(size_t)dm * kH + h] = val;
        }
    }
}

// ---------------------------------------------------------------------------
// Kernel 2 (fused): scores -> softmax -> context, one (b, 4-t tile) per block.
//   1024 threads: s = tid&255, hq = tid>>8 (128-h quarter).
//   Score loop = round-4 form: E packed float4 global loads; P,V via
//   wave-uniform pointers -> scalar-cache s_loads (no VMEM/LDS in loop).
//   tanh(ew+dw) = 1 - 2/(E*P+1); 4-way rcp pairing; SV constant cancels.
//   Context = float4 loads + 8-way s-split LDS tree combine.
// ---------------------------------------------------------------------------
__global__ __launch_bounds__(1024)
void fused_attn_kernel(const float* __restrict__ ewt, const float* __restrict__ dwc,
                       const float* __restrict__ enc, const float* __restrict__ V,
                       const float* __restrict__ mask_f,
                       float* __restrict__ ctx_out, float* __restrict__ attn_out) {
    const int bid = blockIdx.x;
    const int b   = bid & 7;            // XCD-pinned batch
    const int t0  = (bid >> 3) * TM;
    const int tid = threadIdx.x;
    const int s   = tid & 255;
    const int hq  = tid >> 8;           // 0..3 (128 h each)
    const int hqu = __builtin_amdgcn_readfirstlane(hq);  // wave-uniform

    __shared__ union {
        float  part[3 * TM * kTE];      // 12KB score partials
        float4 pctx[4][TM][128];        // 32KB context partial tree
    } u;
    __shared__ float4 wgt4[kTE];        // 4KB softmax weights, t-major
    __shared__ float red_mx[4][TM], red_sm[4][TM];

    // ---- score phase over this thread's 128-h quarter (round-4 form) ----
    const float4* E4 = (const float4*)ewt + ((size_t)(b * 128 + hqu * 32) * 256 + s);
    const float4* Pb = (const float4*)(dwc + (size_t)(b * kTD + t0) * kH) + hqu * 32;
    const float4* V4 = (const float4*)V + hqu * 32;

    float a0 = 0.0f, a1 = 0.0f, a2 = 0.0f, a3 = 0.0f;
    #pragma unroll 4
    for (int g = 0; g < 32; ++g) {
        float4 e  = E4[(size_t)g * 256];
        float4 vv = V4[g];
        {   float4 q = Pb[g];
            float A_ = fmaf(e.x, q.x, 1.0f), B_ = fmaf(e.y, q.y, 1.0f);
            float C_ = fmaf(e.z, q.z, 1.0f), D_ = fmaf(e.w, q.w, 1.0f);
            float t1 = fmaf(vv.y, A_, vv.x * B_);
            float t2 = fmaf(vv.w, C_, vv.z * D_);
            float AB = A_ * B_, CD = C_ * D_;
            float num = fmaf(t2, AB, t1 * CD);
            a0 = fmaf(num, __builtin_amdgcn_rcpf(AB * CD), a0); }
        {   float4 q = Pb[128 + g];
            float A_ = fmaf(e.x, q.x, 1.0f), B_ = fmaf(e.y, q.y, 1.0f);
            float C_ = fmaf(e.z, q.z, 1.0f), D_ = fmaf(e.w, q.w, 1.0f);
            float t1 = fmaf(vv.y, A_, vv.x * B_);
            float t2 = fmaf(vv.w, C_, vv.z * D_);
            float AB = A_ * B_, CD = C_ * D_;
            float num = fmaf(t2, AB, t1 * CD);
            a1 = fmaf(num, __builtin_amdgcn_rcpf(AB * CD), a1); }
        {   float4 q = Pb[256 + g];
            float A_ = fmaf(e.x, q.x, 1.0f), B_ = fmaf(e.y, q.y, 1.0f);
            float C_ = fmaf(e.z, q.z, 1.0f), D_ = fmaf(e.w, q.w, 1.0f);
            float t1 = fmaf(vv.y, A_, vv.x * B_);
            float t2 = fmaf(vv.w, C_, vv.z * D_);
            float AB = A_ * B_, CD = C_ * D_;
            float num = fmaf(t2, AB, t1 * CD);
            a2 = fmaf(num, __builtin_amdgcn_rcpf(AB * CD), a2); }
        {   float4 q = Pb[384 + g];
            float A_ = fmaf(e.x, q.x, 1.0f), B_ = fmaf(e.y, q.y, 1.0f);
            float C_ = fmaf(e.z, q.z, 1.0f), D_ = fmaf(e.w, q.w, 1.0f);
            float t1 = fmaf(vv.y, A_, vv.x * B_);
            float t2 = fmaf(vv.w, C_, vv.z * D_);
            float AB = A_ * B_, CD = C_ * D_;
            float num = fmaf(t2, AB, t1 * CD);
            a3 = fmaf(num, __builtin_amdgcn_rcpf(AB * CD), a3); }
    }

    if (hq > 0) {
        float* pp = &u.part[(hq - 1) * TM * kTE];
        pp[0 * kTE + s] = a0; pp[1 * kTE + s] = a1;
        pp[2 * kTE + s] = a2; pp[3 * kTE + s] = a3;
    }
    __syncthreads();

    const bool active = (hq == 0);
    const int wvq = s >> 6;
    float sc0, sc1, sc2, sc3;
    if (active) {
        const float* P = u.part;
        const float pen = (1.0f - mask_f[b * kTE + s]) * -1e9f;
        sc0 = -2.0f * ((a0 + P[0 * TM * kTE + 0 * kTE + s]) +
                       (P[1 * TM * kTE + 0 * kTE + s] + P[2 * TM * kTE + 0 * kTE + s])) + pen;
        sc1 = -2.0f * ((a1 + P[0 * TM * kTE + 1 * kTE + s]) +
                       (P[1 * TM * kTE + 1 * kTE + s] + P[2 * TM * kTE + 1 * kTE + s])) + pen;
        sc2 = -2.0f * ((a2 + P[0 * TM * kTE + 2 * kTE + s]) +
                       (P[1 * TM * kTE + 2 * kTE + s] + P[2 * TM * kTE + 2 * kTE + s])) + pen;
        sc3 = -2.0f * ((a3 + P[0 * TM * kTE + 3 * kTE + s]) +
                       (P[1 * TM * kTE + 3 * kTE + s] + P[2 * TM * kTE + 3 * kTE + s])) + pen;
        float m0 = sc0, m1 = sc1, m2 = sc2, m3 = sc3;
        #pragma unroll
        for (int off = 1; off < 64; off <<= 1) {
            m0 = fmaxf(m0, __shfl_xor(m0, off));
            m1 = fmaxf(m1, __shfl_xor(m1, off));
            m2 = fmaxf(m2, __shfl_xor(m2, off));
            m3 = fmaxf(m3, __shfl_xor(m3, off));
        }
        if ((s & 63) == 0) {
            red_mx[wvq][0] = m0; red_mx[wvq][1] = m1;
            red_mx[wvq][2] = m2; red_mx[wvq][3] = m3;
        }
    }
    __syncthreads();

    float p0, p1, p2, p3;
    if (active) {
        float m0 = fmaxf(fmaxf(red_mx[0][0], red_mx[1][0]), fmaxf(red_mx[2][0], red_mx[3][0]));
        float m1 = fmaxf(fmaxf(red_mx[0][1], red_mx[1][1]), fmaxf(red_mx[2][1], red_mx[3][1]));
        float m2 = fmaxf(fmaxf(red_mx[0][2], red_mx[1][2]), fmaxf(red_mx[2][2], red_mx[3][2]));
        float m3 = fmaxf(fmaxf(red_mx[0][3], red_mx[1][3]), fmaxf(red_mx[2][3], red_mx[3][3]));
        p0 = __builtin_amdgcn_exp2f((sc0 - m0) * kLog2e);
        p1 = __builtin_amdgcn_exp2f((sc1 - m1) * kLog2e);
        p2 = __builtin_amdgcn_exp2f((sc2 - m2) * kLog2e);
        p3 = __builtin_amdgcn_exp2f((sc3 - m3) * kLog2e);
        float s0 = p0, s1 = p1, s2 = p2, s3 = p3;
        #pragma unroll
        for (int off = 1; off < 64; off <<= 1) {
            s0 += __shfl_xor(s0, off);
            s1 += __shfl_xor(s1, off);
            s2 += __shfl_xor(s2, off);
            s3 += __shfl_xor(s3, off);
        }
        if ((s & 63) == 0) {
            red_sm[wvq][0] = s0; red_sm[wvq][1] = s1;
            red_sm[wvq][2] = s2; red_sm[wvq][3] = s3;
        }
    }
    __syncthreads();

    if (active) {
        float s0 = (red_sm[0][0] + red_sm[1][0]) + (red_sm[2][0] + red_sm[3][0]);
        float s1 = (red_sm[0][1] + red_sm[1][1]) + (red_sm[2][1] + red_sm[3][1]);
        float s2 = (red_sm[0][2] + red_sm[1][2]) + (red_sm[2][2] + red_sm[3][2]);
        float s3 = (red_sm[0][3] + red_sm[1][3]) + (red_sm[2][3] + red_sm[3][3]);
        float4 w;
        w.x = p0 * __builtin_amdgcn_rcpf(s0);
        w.y = p1 * __builtin_amdgcn_rcpf(s1);
        w.z = p2 * __builtin_amdgcn_rcpf(s2);
        w.w = p3 * __builtin_amdgcn_rcpf(s3);
        wgt4[s] = w;
        float* ao = attn_out + (size_t)(b * kTD + t0) * kTE + s;
        ao[0]       = w.x;
        ao[kTE]     = w.y;
        ao[2 * kTE] = w.z;
        ao[3 * kTE] = w.w;
    }
    __syncthreads();

    // ---- context phase: thread = (h-float4, s-octant); float4 loads ----
    const int th4 = tid & 127;           // h quad 0..127
    const int sq  = tid >> 7;            // s octant 0..7
    const float4* enc4 = (const float4*)(enc + (size_t)b * kTE * kH);
    float4 c[TM];
    #pragma unroll
    for (int t = 0; t < TM; ++t) c[t] = float4{0.f, 0.f, 0.f, 0.f};
    #pragma unroll 4
    for (int i = 0; i < 32; ++i) {
        const int ss = sq * 32 + i;
        float4 e = enc4[(size_t)ss * 128 + th4];
        float4 w = wgt4[ss];
        c[0].x = fmaf(w.x, e.x, c[0].x); c[0].y = fmaf(w.x, e.y, c[0].y);
        c[0].z = fmaf(w.x, e.z, c[0].z); c[0].w = fmaf(w.x, e.w, c[0].w);
        c[1].x = fmaf(w.y, e.x, c[1].x); c[1].y = fmaf(w.y, e.y, c[1].y);
        c[1].z = fmaf(w.y, e.z, c[1].z); c[1].w = fmaf(w.y, e.w, c[1].w);
        c[2].x = fmaf(w.z, e.x, c[2].x); c[2].y = fmaf(w.z, e.y, c[2].y);
        c[2].z = fmaf(w.z, e.z, c[2].z); c[2].w = fmaf(w.z, e.w, c[2].w);
        c[3].x = fmaf(w.w, e.x, c[3].x); c[3].y = fmaf(w.w, e.y, c[3].y);
        c[3].z = fmaf(w.w, e.z, c[3].z); c[3].w = fmaf(w.w, e.w, c[3].w);
    }
    // tree combine: 8 -> 4 -> 1
    if (sq >= 4) {
        #pragma unroll
        for (int t = 0; t < TM; ++t) u.pctx[sq - 4][t][th4] = c[t];
    }
    __syncthreads();
    if (sq < 4) {
        #pragma unroll
        for (int t = 0; t < TM; ++t) {
            float4 p = u.pctx[sq][t][th4];
            c[t].x += p.x; c[t].y += p.y; c[t].z += p.z; c[t].w += p.w;
        }
    }
    __syncthreads();
    if (sq >= 1 && sq < 4) {
        #pragma unroll
        for (int t = 0; t < TM; ++t) u.pctx[sq - 1][t][th4] = c[t];
    }
    __syncthreads();
    if (sq == 0) {
        #pragma unroll
        for (int t = 0; t < TM; ++t) {
            float4 q0v = u.pctx[0][t][th4];
            float4 q1v = u.pctx[1][t][th4];
            float4 q2v = u.pctx[2][t][th4];
            c[t].x += (q0v.x + q1v.x) + q2v.x;
            c[t].y += (q0v.y + q1v.y) + q2v.y;
            c[t].z += (q0v.z + q1v.z) + q2v.z;
            c[t].w += (q0v.w + q1v.w) + q2v.w;
            *(float4*)&ctx_out[(size_t)(b * kTD + t0 + t) * kH + th4 * 4] = c[t];
        }
    }
}

// ---------------------------------------------------------------------------
extern "C" void kernel_launch(void* const* d_in, const int* in_sizes, int n_in,
                              void* d_out, int out_size, void* d_ws, size_t ws_size,
                              hipStream_t stream) {
    const float* enc  = (const float*)d_in[0];   // [B, TE, H]
    const float* dec  = (const float*)d_in[1];   // [B, TD, H]
    const void*  mask = d_in[2];                 // [B, TE] bool
    const float* W1   = (const float*)d_in[3];
    const float* W2   = (const float*)d_in[4];
    const float* V    = (const float*)d_in[5];   // [H, 1]

    float* ctx_out  = (float*)d_out;                     // [B, TD, H]
    float* attn_out = (float*)d_out + kB * kTD * kH;     // [B, TD, TE]

    char* ws = (char*)d_ws;
    float* mask_f = (float*)ws;                                      // 2048 f
    float* ewt    = (float*)(ws + 8192);                             // E^T packed [b][h/4][s][4]
    float* dwc    = (float*)(ws + 8192 + (size_t)kB * kTE * kH * 4); // P[t][h]

    hipLaunchKernelGGL(prep_kernel, dim3(GEMM_BLOCKS + 1), dim3(256), 0, stream,
                       enc, dec, W1, W2, mask, ewt, dwc, mask_f);
    hipLaunchKernelGGL(fused_attn_kernel, dim3(kB * kTD / TM), dim3(1024), 0, stream,
                       ewt, dwc, enc, V, mask_f, ctx_out, attn_out);
}